// Round 5
// baseline (211.796 us; speedup 1.0000x reference)
//
#include <hip/hip_runtime.h>
#include <math.h>

// Side-window filter, 3 iterations fused, FP32, bit-exact vs the np reference:
// each directional conv is a sequential fp32 FMA chain over taps in row-major
// (ky,kx) order, acc starting at 0, weights fp32(1/15), fp32(1/9),
// fp32(fp32(1/9)/9). Verified absmax==0.0 in round 4.
//
// This round: pack two horizontally-adjacent pixels into <2 x float> lanes so
// the chains run on v_pk_fma_f32 (full-rate packed fp32, gfx90a+). Per-lane
// rounding identical to v_fma_f32 and per-accumulator op order unchanged =>
// still bit-exact. Tap pairs (W[p],W[p+1]): p even from the b128-loaded f2
// views; p odd via align-4 f2 LDS loads (ds_read2_b32).

typedef float f2  __attribute__((ext_vector_type(2)));
typedef float f4v __attribute__((ext_vector_type(4)));
typedef float f2u __attribute__((ext_vector_type(2), aligned(4)));

#define TW 64
#define TH 24

__device__ __forceinline__ f2 pkfma(f2 a, f2 b, f2 c) {
    return __builtin_elementwise_fma(a, b, c);
}

// One SWF iteration. X: (H2+4) x (W2+4) fp32 LDS tile (pitch W2+4), zero-pad.
// Y: H2 x W2 (pitch W2), zeroed outside the 768x768 image (gy0,gx0 = global
// coords of Y[0][0]); if LAST, write fp32 to outp (pitch 768).
template<int H2, int W2, bool LAST>
__device__ __forceinline__ void step(const float* __restrict__ X,
                                     float* __restrict__ Y,
                                     float* __restrict__ outp,
                                     int gy0, int gx0, int tid) {
    constexpr int PW = W2 + 4;
    constexpr int SC = W2 / 4;
    constexpr int NSEG = H2 * SC;
    const f2 W15 = {1.0f / 15.0f, 1.0f / 15.0f};
    const f2 W9  = {1.0f / 9.0f,  1.0f / 9.0f};
    const f2 W81 = {(1.0f / 9.0f) / 9.0f, (1.0f / 9.0f) / 9.0f};
    const f2 z2  = {0.0f, 0.0f};

    for (int s = tid; s < NSEG; s += 256) {
        const int y  = s / SC;
        const int xs = (s - y * SC) * 4;

        // accumulators: [pp] = pixel pair (xs+2*pp, xs+2*pp+1)
        f2 aL[2]  = {z2, z2}, aR[2]  = {z2, z2};
        f2 aU[2]  = {z2, z2}, aD[2]  = {z2, z2};
        f2 aNW[2] = {z2, z2}, aNE[2] = {z2, z2};
        f2 aSW[2] = {z2, z2}, aSE[2] = {z2, z2};
        f2 c2[2];

        #pragma unroll
        for (int r = 0; r < 5; r++) {
            const float* rp = X + (y + r) * PW + xs;   // 16B-aligned
            f4v lo = *(const f4v*)rp;          // cols 0..3
            f4v hi = *(const f4v*)(rp + 4);    // cols 4..7
            f2 P[7];                            // P[p] = (W[p], W[p+1])
            P[0] = (f2){lo.x, lo.y};
            P[2] = (f2){lo.z, lo.w};
            P[4] = (f2){hi.x, hi.y};
            P[6] = (f2){hi.z, hi.w};
            P[1] = *(const f2u*)(rp + 1);       // align-4 -> ds_read2_b32
            P[3] = *(const f2u*)(rp + 3);
            P[5] = *(const f2u*)(rp + 5);

            #pragma unroll
            for (int pp = 0; pp < 2; pp++) {
                const int b = 2 * pp;
                // per-accumulator op order: rows ascending (r loop), cols
                // ascending within row — identical to the verified chain.
                aL[pp] = pkfma(W15, P[b + 0], aL[pp]);
                aL[pp] = pkfma(W15, P[b + 1], aL[pp]);
                aL[pp] = pkfma(W15, P[b + 2], aL[pp]);
                aR[pp] = pkfma(W15, P[b + 2], aR[pp]);
                aR[pp] = pkfma(W15, P[b + 3], aR[pp]);
                aR[pp] = pkfma(W15, P[b + 4], aR[pp]);
                if (r < 3) {
                    aU[pp] = pkfma(W15, P[b + 0], aU[pp]);
                    aU[pp] = pkfma(W15, P[b + 1], aU[pp]);
                    aU[pp] = pkfma(W15, P[b + 2], aU[pp]);
                    aU[pp] = pkfma(W15, P[b + 3], aU[pp]);
                    aU[pp] = pkfma(W15, P[b + 4], aU[pp]);
                    aNW[pp] = pkfma(W9,  P[b + 0], aNW[pp]);
                    aNW[pp] = pkfma(W9,  P[b + 1], aNW[pp]);
                    aNW[pp] = pkfma(W9,  P[b + 2], aNW[pp]);
                    aNE[pp] = pkfma(W81, P[b + 0], aNE[pp]);
                    aNE[pp] = pkfma(W81, P[b + 1], aNE[pp]);
                    aNE[pp] = pkfma(W81, P[b + 2], aNE[pp]);
                }
                if (r >= 2) {
                    aD[pp] = pkfma(W15, P[b + 0], aD[pp]);
                    aD[pp] = pkfma(W15, P[b + 1], aD[pp]);
                    aD[pp] = pkfma(W15, P[b + 2], aD[pp]);
                    aD[pp] = pkfma(W15, P[b + 3], aD[pp]);
                    aD[pp] = pkfma(W15, P[b + 4], aD[pp]);
                    aSW[pp] = pkfma(W9,  P[b + 0], aSW[pp]);
                    aSW[pp] = pkfma(W9,  P[b + 1], aSW[pp]);
                    aSW[pp] = pkfma(W9,  P[b + 2], aSW[pp]);
                    aSE[pp] = pkfma(W81, P[b + 0], aSE[pp]);
                    aSE[pp] = pkfma(W81, P[b + 1], aSE[pp]);
                    aSE[pp] = pkfma(W81, P[b + 2], aSE[pp]);
                }
                if (r == 2) c2[pp] = P[b + 2];  // centers (xs+b+2, xs+b+3)
            }
        }

        f4v R;
        #pragma unroll
        for (int pp = 0; pp < 2; pp++) {
            f2 d0 = aL[pp]  - c2[pp], d1 = aR[pp]  - c2[pp];
            f2 d2 = aU[pp]  - c2[pp], d3 = aD[pp]  - c2[pp];
            f2 d4 = aNW[pp] - c2[pp], d5 = aNE[pp] - c2[pp];
            f2 d6 = aSW[pp] - c2[pp], d7 = aSE[pp] - c2[pp];
            #pragma unroll
            for (int h = 0; h < 2; h++) {
                const float e0 = d0[h], e1 = d1[h], e2 = d2[h], e3 = d3[h];
                const float e4 = d4[h], e5 = d5[h], e6 = d6[h], e7 = d7[h];
                // tournament argmin on |d|, strict < keeps lowest index on
                // ties (matches jnp.argmin); |x| folds into VOP3 abs mods
                float m01 = (fabsf(e1) < fabsf(e0)) ? e1 : e0;
                float m23 = (fabsf(e3) < fabsf(e2)) ? e3 : e2;
                float m45 = (fabsf(e5) < fabsf(e4)) ? e5 : e4;
                float m67 = (fabsf(e7) < fabsf(e6)) ? e7 : e6;
                float mA  = (fabsf(m23) < fabsf(m01)) ? m23 : m01;
                float mB  = (fabsf(m67) < fabsf(m45)) ? m67 : m45;
                float bd  = (fabsf(mB)  < fabsf(mA))  ? mB  : mA;
                const float res = c2[pp][h] + bd;
                if (pp == 0) { if (h == 0) R.x = res; else R.y = res; }
                else         { if (h == 0) R.z = res; else R.w = res; }
            }
        }

        if (LAST) {
            *(f4v*)(outp + y * 768 + xs) = R;
        } else {
            // zero outside the image: next iteration zero-pads at the boundary
            const bool rowin = ((unsigned)(gy0 + y) < 768u);
            if (!(rowin && (unsigned)(gx0 + xs) < 768u &&
                           (unsigned)(gx0 + xs + 3) < 768u)) {
                R.x = (rowin && (unsigned)(gx0 + xs + 0) < 768u) ? R.x : 0.0f;
                R.y = (rowin && (unsigned)(gx0 + xs + 1) < 768u) ? R.y : 0.0f;
                R.z = (rowin && (unsigned)(gx0 + xs + 2) < 768u) ? R.z : 0.0f;
                R.w = (rowin && (unsigned)(gx0 + xs + 3) < 768u) ? R.w : 0.0f;
            }
            *(f4v*)(Y + y * W2 + xs) = R;
        }
    }
    __syncthreads();
}

// LDS: A = 36x76 fp32 (iter1 input; reused as iter2 output 28x68),
//      B = 32x72 fp32 (iter1 output = iter2 input). 20160 B total.
__global__ __launch_bounds__(256) void swf_fused(const float* __restrict__ in,
                                                 float* __restrict__ out) {
    __shared__ __align__(16) float A[36 * 76];
    __shared__ __align__(16) float B[32 * 72];

    const int tid = threadIdx.x;
    const int tx0 = blockIdx.x * TW;
    const int ty0 = blockIdx.y * TH;
    const long long base = (long long)blockIdx.z * (768 * 768);
    const float* inp = in + base;

    // load tile rows ty0-6..ty0+29, cols tx0-6..tx0+69, zero-padded
    for (int i = tid; i < 36 * 76; i += 256) {
        int ly = i / 76, lx = i - ly * 76;
        int gy = ty0 + ly - 6, gx = tx0 + lx - 6;
        float v = 0.0f;
        if ((unsigned)gy < 768u && (unsigned)gx < 768u)
            v = inp[gy * 768 + gx];
        A[i] = v;
    }
    __syncthreads();

    step<32, 72, false>(A, B, nullptr, ty0 - 4, tx0 - 4, tid);  // iter1: A->B
    step<28, 68, false>(B, A, nullptr, ty0 - 2, tx0 - 2, tid);  // iter2: B->A
    step<24, 64, true >(A, nullptr,                              // iter3: A->out
                        out + base + (long long)ty0 * 768 + tx0, ty0, tx0, tid);
}

extern "C" void kernel_launch(void* const* d_in, const int* in_sizes, int n_in,
                              void* d_out, int out_size, void* d_ws, size_t ws_size,
                              hipStream_t stream) {
    const float* x = (const float*)d_in[0];
    float* out = (float*)d_out;

    dim3 grid(768 / TW, 768 / TH, 24);   // 12 x 32 x 24 blocks
    dim3 block(256);
    swf_fused<<<grid, block, 0, stream>>>(x, out);
}

// Round 6
// 202.247 us; speedup vs baseline: 1.0472x; 1.0472x over previous
//
#include <hip/hip_runtime.h>
#include <math.h>

// Side-window filter, 3 iterations fused, FP32, bit-exact vs the np reference
// (verified absmax==0.0 in round 4): each directional conv is a sequential
// fp32 FMA chain over taps in row-major (ky,kx) order, acc starting at 0,
// weights fp32(1/15), fp32(1/9), fp32(fp32(1/9)/9). Zero-padded taps are exact
// no-ops. Intermediates fp32; out-of-image intermediate pixels zeroed (next
// iteration zero-pads at the image boundary).
//
// Round 6: 64x64 output tile (halo recompute 1.247x -> 1.131x), scalar FMA
// chains (packed fp32 was measured issue-neutral on CDNA4 datapath),
// row-streaming inner loop (8 window floats live at a time, 32 accumulators),
// block-uniform interior fast path for stores, float2 staging loads.
//
// Direction supports (with the reference's normalization bug):
//   d0 L  = rows[-2..2] x cols[-2..0] * (1/15)
//   d1 R  = rows[-2..2] x cols[0..2]  * (1/15)
//   d2 U  = rows[-2..0] x cols[-2..2] * (1/15)
//   d3 D  = rows[0..2]  x cols[-2..2] * (1/15)
//   d4 NW = rows[-2..0] x cols[-2..0] * (1/9)
//   d5 NE = NW support * (1/81)   (bug: NE = new NW / 9)
//   d6 SW = rows[0..2]  x cols[-2..0] * (1/9)
//   d7 SE = SW support * (1/81)   (bug: SE = new SW / 9)

typedef float f4v __attribute__((ext_vector_type(4)));
typedef float f2v __attribute__((ext_vector_type(2), aligned(8)));

#define TW 64
#define TH 64

// One SWF iteration. X: (H2+4) x (W2+4) fp32 LDS tile (pitch W2+4), zero-pad.
// Y: H2 x W2 (pitch W2), zeroed outside the 768x768 image (gy0,gx0 = global
// coords of Y[0][0]); if LAST, write fp32 to outp (pitch 768).
template<int H2, int W2, bool LAST>
__device__ __forceinline__ void step(const float* __restrict__ X,
                                     float* __restrict__ Y,
                                     float* __restrict__ outp,
                                     int gy0, int gx0, int tid) {
    constexpr int PW = W2 + 4;
    constexpr int SC = W2 / 4;
    constexpr int NSEG = H2 * SC;
    const float w15 = 1.0f / 15.0f;
    const float w9  = 1.0f / 9.0f;
    const float w81 = (1.0f / 9.0f) / 9.0f;

    // block-uniform: every output pixel of this step inside the image?
    const bool interior = (gy0 >= 0) && (gx0 >= 0) &&
                          (gy0 + H2 <= 768) && (gx0 + W2 <= 768);

    for (int s = tid; s < NSEG; s += 256) {
        const int y  = s / SC;
        const int xs = (s - y * SC) * 4;
        const float* rp = X + y * PW + xs;

        // acc[dir][px]; per-accumulator op order = rows ascending (r loop),
        // cols ascending within row — the verified bit-exact chain.
        float acc[8][4];
        #pragma unroll
        for (int d = 0; d < 8; d++)
            #pragma unroll
            for (int j = 0; j < 4; j++) acc[d][j] = 0.0f;
        float ctr[4];

        #pragma unroll
        for (int r = 0; r < 5; r++) {
            const float* p = rp + r * PW;     // 16B-aligned
            f4v lo = *(const f4v*)p;
            f4v hi = *(const f4v*)(p + 4);
            float w[8] = {lo.x, lo.y, lo.z, lo.w, hi.x, hi.y, hi.z, hi.w};

            #pragma unroll
            for (int j = 0; j < 4; j++) {
                // full-height: L (cols j..j+2), R (cols j+2..j+4)
                acc[0][j] = fmaf(w15, w[j + 0], acc[0][j]);
                acc[0][j] = fmaf(w15, w[j + 1], acc[0][j]);
                acc[0][j] = fmaf(w15, w[j + 2], acc[0][j]);
                acc[1][j] = fmaf(w15, w[j + 2], acc[1][j]);
                acc[1][j] = fmaf(w15, w[j + 3], acc[1][j]);
                acc[1][j] = fmaf(w15, w[j + 4], acc[1][j]);
                if (r < 3) {  // U, NW, NE
                    acc[2][j] = fmaf(w15, w[j + 0], acc[2][j]);
                    acc[2][j] = fmaf(w15, w[j + 1], acc[2][j]);
                    acc[2][j] = fmaf(w15, w[j + 2], acc[2][j]);
                    acc[2][j] = fmaf(w15, w[j + 3], acc[2][j]);
                    acc[2][j] = fmaf(w15, w[j + 4], acc[2][j]);
                    acc[4][j] = fmaf(w9,  w[j + 0], acc[4][j]);
                    acc[4][j] = fmaf(w9,  w[j + 1], acc[4][j]);
                    acc[4][j] = fmaf(w9,  w[j + 2], acc[4][j]);
                    acc[5][j] = fmaf(w81, w[j + 0], acc[5][j]);
                    acc[5][j] = fmaf(w81, w[j + 1], acc[5][j]);
                    acc[5][j] = fmaf(w81, w[j + 2], acc[5][j]);
                }
                if (r >= 2) {  // D, SW, SE
                    acc[3][j] = fmaf(w15, w[j + 0], acc[3][j]);
                    acc[3][j] = fmaf(w15, w[j + 1], acc[3][j]);
                    acc[3][j] = fmaf(w15, w[j + 2], acc[3][j]);
                    acc[3][j] = fmaf(w15, w[j + 3], acc[3][j]);
                    acc[3][j] = fmaf(w15, w[j + 4], acc[3][j]);
                    acc[6][j] = fmaf(w9,  w[j + 0], acc[6][j]);
                    acc[6][j] = fmaf(w9,  w[j + 1], acc[6][j]);
                    acc[6][j] = fmaf(w9,  w[j + 2], acc[6][j]);
                    acc[7][j] = fmaf(w81, w[j + 0], acc[7][j]);
                    acc[7][j] = fmaf(w81, w[j + 1], acc[7][j]);
                    acc[7][j] = fmaf(w81, w[j + 2], acc[7][j]);
                }
                if (r == 2) ctr[j] = w[j + 2];
            }
        }

        f4v R;
        #pragma unroll
        for (int j = 0; j < 4; j++) {
            const float c = ctr[j];
            const float e0 = acc[0][j] - c, e1 = acc[1][j] - c;
            const float e2 = acc[2][j] - c, e3 = acc[3][j] - c;
            const float e4 = acc[4][j] - c, e5 = acc[5][j] - c;
            const float e6 = acc[6][j] - c, e7 = acc[7][j] - c;
            // tournament argmin on |d|; strict < keeps lowest index on ties
            // (matches jnp.argmin); |x| folds into VOP3 abs modifiers
            float m01 = (fabsf(e1) < fabsf(e0)) ? e1 : e0;
            float m23 = (fabsf(e3) < fabsf(e2)) ? e3 : e2;
            float m45 = (fabsf(e5) < fabsf(e4)) ? e5 : e4;
            float m67 = (fabsf(e7) < fabsf(e6)) ? e7 : e6;
            float mA  = (fabsf(m23) < fabsf(m01)) ? m23 : m01;
            float mB  = (fabsf(m67) < fabsf(m45)) ? m67 : m45;
            float bd  = (fabsf(mB)  < fabsf(mA))  ? mB  : mA;
            const float res = c + bd;
            if (j == 0) R.x = res; else if (j == 1) R.y = res;
            else if (j == 2) R.z = res; else R.w = res;
        }

        if (LAST) {
            *(f4v*)(outp + y * 768 + xs) = R;
        } else if (interior) {
            *(f4v*)(Y + y * W2 + xs) = R;
        } else {
            // zero outside the image: next iteration zero-pads at the boundary
            const bool rowin = ((unsigned)(gy0 + y) < 768u);
            R.x = (rowin && (unsigned)(gx0 + xs + 0) < 768u) ? R.x : 0.0f;
            R.y = (rowin && (unsigned)(gx0 + xs + 1) < 768u) ? R.y : 0.0f;
            R.z = (rowin && (unsigned)(gx0 + xs + 2) < 768u) ? R.z : 0.0f;
            R.w = (rowin && (unsigned)(gx0 + xs + 3) < 768u) ? R.w : 0.0f;
            *(f4v*)(Y + y * W2 + xs) = R;
        }
    }
    __syncthreads();
}

// LDS: A = 76x76 fp32 (iter1 input; reused as iter2 output 68x68) = 23104 B,
//      B = 72x72 fp32 (iter1 output = iter2 input) = 20736 B. Total 43840 B
//      -> 3 blocks/CU (12 waves/CU).
__global__ __launch_bounds__(256) void swf_fused(const float* __restrict__ in,
                                                 float* __restrict__ out) {
    __shared__ __align__(16) float A[76 * 76];
    __shared__ __align__(16) float B[72 * 72];

    const int tid = threadIdx.x;
    const int tx0 = blockIdx.x * TW;
    const int ty0 = blockIdx.y * TH;
    const long long base = (long long)blockIdx.z * (768 * 768);
    const float* inp = in + base;

    // load tile rows ty0-6..ty0+69, cols tx0-6..tx0+69, zero-padded.
    // float2 granularity: global col tx0-6 is even -> 8B aligned.
    for (int i = tid; i < 76 * 38; i += 256) {
        const int ly  = i / 38;
        const int lx2 = i - ly * 38;
        const int gy  = ty0 + ly - 6;
        const int gx  = tx0 + lx2 * 2 - 6;
        f2v v = {0.0f, 0.0f};
        if ((unsigned)gy < 768u) {
            const float* g = inp + gy * 768 + gx;
            if ((unsigned)gx < 767u) {            // both lanes inside
                v = *(const f2v*)g;
            } else {                               // x-edge: per-lane
                if ((unsigned)gx < 768u)       v.x = g[0];
                if ((unsigned)(gx + 1) < 768u) v.y = g[1];
            }
        }
        *(f2v*)(A + ly * 76 + lx2 * 2) = v;
    }
    __syncthreads();

    step<72, 72, false>(A, B, nullptr, ty0 - 4, tx0 - 4, tid);  // iter1: A->B
    step<68, 68, false>(B, A, nullptr, ty0 - 2, tx0 - 2, tid);  // iter2: B->A
    step<64, 64, true >(A, nullptr,                              // iter3: A->out
                        out + base + (long long)ty0 * 768 + tx0, ty0, tx0, tid);
}

extern "C" void kernel_launch(void* const* d_in, const int* in_sizes, int n_in,
                              void* d_out, int out_size, void* d_ws, size_t ws_size,
                              hipStream_t stream) {
    const float* x = (const float*)d_in[0];
    float* out = (float*)d_out;

    dim3 grid(768 / TW, 768 / TH, 24);   // 12 x 12 x 24 = 3456 blocks
    dim3 block(256);
    swf_fused<<<grid, block, 0, stream>>>(x, out);
}